// Round 14
// baseline (313.088 us; speedup 1.0000x reference)
//
#include <hip/hip_runtime.h>
#include <hip/hip_bf16.h>
#include <cmath>

// B=128, T=256, D=1024, V=32000, E=300
// d_out (floats): logits[0..4096000), h_new[4096000), c_new[4227072),
//                 attn[4358144), context[4390912), total 4521984

#define Bc 128
#define Tc 256
#define Dc 1024
#define Vc 32000
#define Ec 300
#define KREAL 2348        // D + E + D
#define KXP 2688          // padded: 7 splits x 6 steps x 64
#define KSPLIT 7
#define N4 4096

typedef __attribute__((ext_vector_type(8))) short bf16x8;
typedef __attribute__((ext_vector_type(4))) float f32x4;

static __device__ __forceinline__ short f2bf(float x) {
    __hip_bfloat16 b = __float2bfloat16(x);   // RNE
    return *reinterpret_cast<short*>(&b);
}
static __device__ __forceinline__ unsigned pack2(float a, float b) {
    return (unsigned)(unsigned short)f2bf(a) | ((unsigned)(unsigned short)f2bf(b) << 16);
}

// ---- A (att1 + last-block att2): grid (4,128) x 256. ----
// Each block: scores + ctx partial for 64 t's (enc read once, from registers).
// The LAST block of each b (device-scope counter) reduces ctx, does softmax,
// packs x_bf16 — overlapping what used to be a separate kernel + boundary.
__global__ void k_att1f(const float* __restrict__ enc, const float* __restrict__ h,
                        const int* __restrict__ idx, const float* __restrict__ emb_table,
                        float* __restrict__ scores_g, float* __restrict__ ctx_part,
                        float* __restrict__ ctx_out, float* __restrict__ attn_out,
                        unsigned short* __restrict__ x_bf, int* __restrict__ cnt) {
    const int tc = blockIdx.x;            // 0..3 (64-row chunk)
    const int b  = blockIdx.y;
    const int tid = threadIdx.x;
    const int wave = tid >> 6, lane = tid & 63;
    __shared__ float s_acc[4][1024];      // 16 KB
    __shared__ float red[256];
    __shared__ int s_last;

    const float4* h4 = (const float4*)(h + ((size_t)b << 10));
    float4 hv0 = h4[lane], hv1 = h4[lane + 64], hv2 = h4[lane + 128], hv3 = h4[lane + 192];

    float4 a0 = {0,0,0,0}, a1 = {0,0,0,0}, a2 = {0,0,0,0}, a3 = {0,0,0,0};
    const int t0 = (tc << 6) + (wave << 4);
    const float4* e4 = (const float4*)(enc + ((size_t)(b * Tc + t0) << 10));

    #pragma unroll 2
    for (int i = 0; i < 16; ++i) {
        float4 e0 = e4[lane], e1 = e4[lane + 64], e2 = e4[lane + 128], e3 = e4[lane + 192];
        e4 += 256;
        float d = e0.x*hv0.x + e0.y*hv0.y + e0.z*hv0.z + e0.w*hv0.w
                + e1.x*hv1.x + e1.y*hv1.y + e1.z*hv1.z + e1.w*hv1.w
                + e2.x*hv2.x + e2.y*hv2.y + e2.z*hv2.z + e2.w*hv2.w
                + e3.x*hv3.x + e3.y*hv3.y + e3.z*hv3.z + e3.w*hv3.w;
        #pragma unroll
        for (int off = 32; off; off >>= 1) d += __shfl_xor(d, off, 64);
        if (lane == 0) scores_g[(b << 8) + t0 + i] = d;
        a0.x += d*e0.x; a0.y += d*e0.y; a0.z += d*e0.z; a0.w += d*e0.w;
        a1.x += d*e1.x; a1.y += d*e1.y; a1.z += d*e1.z; a1.w += d*e1.w;
        a2.x += d*e2.x; a2.y += d*e2.y; a2.z += d*e2.z; a2.w += d*e2.w;
        a3.x += d*e3.x; a3.y += d*e3.y; a3.z += d*e3.z; a3.w += d*e3.w;
    }

    *(float4*)&s_acc[wave][lane << 2]         = a0;
    *(float4*)&s_acc[wave][256 + (lane << 2)] = a1;
    *(float4*)&s_acc[wave][512 + (lane << 2)] = a2;
    *(float4*)&s_acc[wave][768 + (lane << 2)] = a3;
    __syncthreads();
    {
        float4 r0 = *(const float4*)&s_acc[0][tid << 2];
        float4 r1 = *(const float4*)&s_acc[1][tid << 2];
        float4 r2 = *(const float4*)&s_acc[2][tid << 2];
        float4 r3 = *(const float4*)&s_acc[3][tid << 2];
        float4 r;
        r.x = r0.x + r1.x + r2.x + r3.x;
        r.y = r0.y + r1.y + r2.y + r3.y;
        r.z = r0.z + r1.z + r2.z + r3.z;
        r.w = r0.w + r1.w + r2.w + r3.w;
        *(float4*)(ctx_part + (((size_t)(tc << 7) + b) << 10) + (tid << 2)) = r;
    }

    // ---- last-block election (release: stores above; acquire in finisher) ----
    __threadfence();
    if (tid == 0) s_last = (atomicAdd(&cnt[b], 1) == 3);
    __syncthreads();
    if (!s_last) return;
    __threadfence();

    // ---- att2 body for this b (256 threads) ----
    float4 cv = {0.f, 0.f, 0.f, 0.f};
    #pragma unroll
    for (int t4 = 0; t4 < 4; ++t4) {
        float4 s = *(const float4*)(ctx_part + (((size_t)(t4 << 7) + b) << 10) + (tid << 2));
        cv.x += s.x; cv.y += s.y; cv.z += s.z; cv.w += s.w;
    }
    *(float4*)(ctx_out + ((size_t)b << 10) + (tid << 2)) = cv;

    unsigned short* xb = x_bf + (size_t)b * KXP;
    uint2 p0; p0.x = pack2(cv.x, cv.y); p0.y = pack2(cv.z, cv.w);
    *(uint2*)&xb[tid << 2] = p0;

    int row = idx[b];
    for (int i = tid; i < Ec; i += 256)
        xb[Dc + i] = (unsigned short)f2bf(emb_table[(size_t)row * Ec + i]);

    float4 hv = *(const float4*)(h + ((size_t)b << 10) + (tid << 2));
    uint2 p1; p1.x = pack2(hv.x, hv.y); p1.y = pack2(hv.z, hv.w);
    *(uint2*)&xb[(Dc + Ec) + (tid << 2)] = p1;

    for (int i = tid; i < KXP - KREAL; i += 256) xb[KREAL + i] = 0;

    float v = scores_g[(b << 8) + tid];
    red[tid] = v;
    __syncthreads();
    for (int s = 128; s; s >>= 1) { if (tid < s) red[tid] = fmaxf(red[tid], red[tid + s]); __syncthreads(); }
    float m = red[0];
    __syncthreads();
    float e = __expf(v - m);
    red[tid] = e;
    __syncthreads();
    for (int s = 128; s; s >>= 1) { if (tid < s) red[tid] += red[tid + s]; __syncthreads(); }
    attn_out[(b << 8) + tid] = e / red[0];
}

// ---- Z (zgemm + last-block gates): grid (64,7) x 512. R7 zgemm body;
// the 28th block (7 ksp x 4 n-tiles) per d-block does gates for 64 d x 128 b. ----
__global__ __launch_bounds__(512) void k_zgf(
        const unsigned short* __restrict__ xbf, const float* __restrict__ Wl,
        const float* __restrict__ Ul, float* __restrict__ z_part,
        const float* __restrict__ bl, const float* __restrict__ c_in,
        float* __restrict__ h_new, float* __restrict__ c_new,
        unsigned short* __restrict__ h_bf, int* __restrict__ cnt2) {
    __shared__ __align__(16) short blds[2 * 8 * 64 * 8];   // 16 KB
    __shared__ int s_last;
    const int tid  = threadIdx.x;
    const int wid  = tid >> 6;
    const int lane = tid & 63;
    const int g    = lane >> 4;
    const int r    = lane & 15;
    const int n0   = blockIdx.x << 6;     // 64-wide n tile
    const int ksp  = blockIdx.y;          // 0..6, steps ksp*6 .. ksp*6+5

    const int pr = tid >> 4;
    const int c  = tid & 15;
    const int kk = (pr << 1) & 31;
    const int gg = kk >> 3, jj = kk & 7;
    const int ks0 = pr >> 4;              // 0 or 1

    f32x4 acc[4] = {};
    const unsigned short* xrow = xbf + (size_t)((wid << 4) + r) * KXP;

    float4 wra[2], wrb[2];
    bf16x8 areg[2][2];

    auto loadWU = [&](int gk) -> float4 {
        if (gk < 1324) return *(const float4*)(Wl + (size_t)gk * N4 + n0 + (c << 2));
        if (gk < KREAL) return *(const float4*)(Ul + (size_t)(gk - 1324) * N4 + n0 + (c << 2));
        return float4{0.f, 0.f, 0.f, 0.f};
    };

    {
        const int kt = (ksp * 6) << 6;
        wra[0] = loadWU(kt + (pr << 1));
        wrb[0] = loadWU(kt + (pr << 1) + 1);
        areg[0][0] = *(const bf16x8*)&xrow[kt + (g << 3)];
        areg[0][1] = *(const bf16x8*)&xrow[kt + 32 + (g << 3)];
    }

    #pragma unroll
    for (int t = 0; t < 6; ++t) {
        const int cur = t & 1;
        const int coff = cur << 12;       // shorts
        {
            const float av[4] = {wra[cur].x, wra[cur].y, wra[cur].z, wra[cur].w};
            const float bv[4] = {wrb[cur].x, wrb[cur].y, wrb[cur].z, wrb[cur].w};
            #pragma unroll
            for (int i = 0; i < 4; ++i) {
                int n = (c << 2) + i;
                int nt = n >> 4;
                int inner = (gg << 4) | (n & 15);
                int Xs = ((((ks0 << 2) + nt) << 6) | inner) ^ nt;
                *(unsigned*)&blds[coff + (Xs << 3) + jj] = pack2(av[i], bv[i]);
            }
        }
        if (t < 5) {
            const int kt = ((ksp * 6) + t + 1) << 6;
            wra[cur ^ 1] = loadWU(kt + (pr << 1));
            wrb[cur ^ 1] = loadWU(kt + (pr << 1) + 1);
            areg[cur ^ 1][0] = *(const bf16x8*)&xrow[kt + (g << 3)];
            areg[cur ^ 1][1] = *(const bf16x8*)&xrow[kt + 32 + (g << 3)];
        }
        __syncthreads();
        #pragma unroll
        for (int ks = 0; ks < 2; ++ks) {
            #pragma unroll
            for (int nt = 0; nt < 4; ++nt) {
                int Xs = ((((ks << 2) + nt) << 6) | lane) ^ nt;
                bf16x8 bfr = *(const bf16x8*)&blds[coff + (Xs << 3)];
                acc[nt] = __builtin_amdgcn_mfma_f32_16x16x32_bf16(areg[cur][ks], bfr, acc[nt], 0, 0, 0);
            }
        }
    }

    float* zp = z_part + ((size_t)ksp << 19);
    #pragma unroll
    for (int nt = 0; nt < 4; ++nt) {
        int col = n0 + (nt << 4) + r;
        #pragma unroll
        for (int j = 0; j < 4; ++j) {
            int rowm = (wid << 4) + (g << 2) + j;
            zp[((size_t)rowm << 12) + col] = acc[nt][j];
        }
    }

    // ---- last-block election per d-block (j & 15): 28 contributors ----
    const int db = blockIdx.x & 15;
    __threadfence();
    if (tid == 0) s_last = (atomicAdd(&cnt2[db], 1) == 27);
    __syncthreads();
    if (!s_last) return;
    __threadfence();

    // ---- gates for d in [db*64, db*64+64), all b (512 threads x 16 iters) ----
    const int dbase = db << 6;
    #pragma unroll 2
    for (int it = 0; it < 16; ++it) {
        int i = (it << 9) + tid;          // 0..8191
        int b = i >> 6, dl = i & 63;
        int d = dbase + dl;
        size_t base = ((size_t)b << 12) + d;
        float zi = bl[d], zf = bl[d + 1024], zg = bl[d + 2048], zo = bl[d + 3072];
        #pragma unroll
        for (int ks = 0; ks < KSPLIT; ++ks) {
            const float* zq = z_part + ((size_t)ks << 19);
            zi += zq[base];
            zf += zq[base + 1024];
            zg += zq[base + 2048];
            zo += zq[base + 3072];
        }
        float si = 1.f / (1.f + __expf(-zi));
        float sf = 1.f / (1.f + __expf(-zf));
        float so = 1.f / (1.f + __expf(-zo));
        float cn = sf * c_in[(b << 10) + d] + si * tanhf(zg);
        float hn = so * tanhf(cn);
        c_new[(b << 10) + d] = cn;
        h_new[(b << 10) + d] = hn;
        h_bf[(b << 10) + d] = (unsigned short)f2bf(hn);
    }
}

// ---- L: logits, bf16 MFMA, K-step 128, N-tile 64, LDS dbuf + early-issue.
//      500 blocks x 512 threads, ONE barrier per K-step (exact R7). ----
__global__ __launch_bounds__(512) void k_logits_mfma(
        const unsigned short* __restrict__ hbf, const float* __restrict__ Wd,
        const float* __restrict__ bd, float* __restrict__ out) {
    __shared__ __align__(16) short blds[2 * 16 * 64 * 8];   // 32 KB
    const int tid  = threadIdx.x;
    const int wid  = tid >> 6;
    const int lane = tid & 63;
    const int g    = lane >> 4;
    const int r    = lane & 15;
    const int n0   = blockIdx.x << 6;     // 64-wide n tile

    const int pr = tid >> 4;              // 0..31
    const int c  = tid & 15;
    const int kk = (pr << 1) & 31;
    const int gg = kk >> 3, jj = kk & 7;
    const int ksA = pr >> 4;              // task0: 0..1
    const int ksB = ksA + 2;              // task1: 2..3

    f32x4 acc[4] = {};
    const unsigned short* hrow = hbf + ((size_t)((wid << 4) + r) << 10);
    const float* wbase = Wd + (size_t)(pr << 1) * Vc + n0 + (c << 2);

    float4 wra[2], wrb[2], wrc[2], wrd[2];
    bf16x8 areg[2][4];

    {
        wra[0] = *(const float4*)(wbase);
        wrb[0] = *(const float4*)(wbase + Vc);
        wrc[0] = *(const float4*)(wbase + (size_t)64 * Vc);
        wrd[0] = *(const float4*)(wbase + (size_t)65 * Vc);
        #pragma unroll
        for (int ks = 0; ks < 4; ++ks)
            areg[0][ks] = *(const bf16x8*)&hrow[(ks << 5) + (g << 3)];
    }

    #pragma unroll
    for (int t = 0; t < 8; ++t) {
        const int cur = t & 1;
        const int coff = cur << 13;       // shorts
        {
            const float a0[4] = {wra[cur].x, wra[cur].y, wra[cur].z, wra[cur].w};
            const float b0[4] = {wrb[cur].x, wrb[cur].y, wrb[cur].z, wrb[cur].w};
            const float c0[4] = {wrc[cur].x, wrc[cur].y, wrc[cur].z, wrc[cur].w};
            const float d0[4] = {wrd[cur].x, wrd[cur].y, wrd[cur].z, wrd[cur].w};
            #pragma unroll
            for (int i = 0; i < 4; ++i) {
                int n = (c << 2) + i;
                int nt = n >> 4;
                int inner = (gg << 4) | (n & 15);
                int XsA = ((((ksA << 2) + nt) << 6) | inner) ^ nt;
                int XsB = ((((ksB << 2) + nt) << 6) | inner) ^ nt;
                *(unsigned*)&blds[coff + (XsA << 3) + jj] = pack2(a0[i], b0[i]);
                *(unsigned*)&blds[coff + (XsB << 3) + jj] = pack2(c0[i], d0[i]);
            }
        }
        if (t < 7) {
            const float* wb2 = wbase + (size_t)((t + 1) << 7) * Vc;
            wra[cur ^ 1] = *(const float4*)(wb2);
            wrb[cur ^ 1] = *(const float4*)(wb2 + Vc);
            wrc[cur ^ 1] = *(const float4*)(wb2 + (size_t)64 * Vc);
            wrd[cur ^ 1] = *(const float4*)(wb2 + (size_t)65 * Vc);
            #pragma unroll
            for (int ks = 0; ks < 4; ++ks)
                areg[cur ^ 1][ks] = *(const bf16x8*)&hrow[((t + 1) << 7) + (ks << 5) + (g << 3)];
        }
        __syncthreads();
        #pragma unroll
        for (int ks = 0; ks < 4; ++ks) {
            #pragma unroll
            for (int nt = 0; nt < 4; ++nt) {
                int Xs = ((((ks << 2) + nt) << 6) | lane) ^ nt;
                bf16x8 bfr = *(const bf16x8*)&blds[coff + (Xs << 3)];
                acc[nt] = __builtin_amdgcn_mfma_f32_16x16x32_bf16(areg[cur][ks], bfr, acc[nt], 0, 0, 0);
            }
        }
    }

    #pragma unroll
    for (int nt = 0; nt < 4; ++nt) {
        int col = n0 + (nt << 4) + r;
        float bias = bd[col];
        #pragma unroll
        for (int j = 0; j < 4; ++j) {
            int row = (wid << 4) + (g << 2) + j;
            out[(size_t)row * Vc + col] = acc[nt][j] + bias;
        }
    }
}

extern "C" void kernel_launch(void* const* d_in, const int* in_sizes, int n_in,
                              void* d_out, int out_size, void* d_ws, size_t ws_size,
                              hipStream_t stream) {
    const int*   idx = (const int*)d_in[0];
    const float* enc = (const float*)d_in[1];
    const float* h   = (const float*)d_in[2];
    const float* c   = (const float*)d_in[3];
    const float* emb = (const float*)d_in[4];
    const float* Wl  = (const float*)d_in[5];
    const float* Ul  = (const float*)d_in[6];
    const float* bl  = (const float*)d_in[7];
    const float* Wd  = (const float*)d_in[8];
    const float* bd  = (const float*)d_in[9];

    float* out    = (float*)d_out;
    float* logits = out;                 // 4,096,000
    float* h_new  = out + 4096000;
    float* c_new  = out + 4227072;
    float* attn   = out + 4358144;
    float* ctx    = out + 4390912;

    // Scratch consumed BEFORE k_logits_mfma lives in the logits region;
    // anything k_logits_mfma READS lives in d_ws (it writes [0,4096000)).
    float*          ctx_part = out;                  // 4*131072 = 524,288
    float*          scores_g = out + 524288;         // 32,768 (ends 557,056)
    float*          z_part   = out;                  // 7*524,288 = 3,670,016
    unsigned short* x_bf16   = (unsigned short*)d_ws;            // 344,064 shorts
    unsigned short* h_bf16   = (unsigned short*)d_ws + 344064;   // 131,072 shorts
    int*            cnt      = (int*)((char*)d_ws + 950272);     // 256 ints (1 KB)
    int*            cnt_att  = cnt;                              // [0..127]
    int*            cnt_zg   = cnt + 128;                        // [128..143]

    // zero the completion counters (graph-capturable memset node)
    hipMemsetAsync(cnt, 0, 1024, stream);

    hipLaunchKernelGGL(k_att1f, dim3(4, 128), dim3(256), 0, stream,
                       enc, h, idx, emb, scores_g, ctx_part, ctx, attn, x_bf16, cnt_att);
    hipLaunchKernelGGL(k_zgf, dim3(64, KSPLIT), dim3(512), 0, stream,
                       x_bf16, Wl, Ul, z_part, bl, c, h_new, c_new, h_bf16, cnt_zg);
    hipLaunchKernelGGL(k_logits_mfma, dim3(500), dim3(512), 0, stream, h_bf16, Wd, bd, logits);
}

// Round 15
// 91.396 us; speedup vs baseline: 3.4256x; 3.4256x over previous
//
#include <hip/hip_runtime.h>
#include <hip/hip_bf16.h>
#include <cmath>

// B=128, T=256, D=1024, V=32000, E=300
// d_out (floats): logits[0..4096000), h_new[4096000), c_new[4227072),
//                 attn[4358144), context[4390912), total 4521984

#define Bc 128
#define Tc 256
#define Dc 1024
#define Vc 32000
#define Ec 300
#define KREAL 2348        // D + E + D
#define KXP 2688          // padded: 7 splits x 6 steps x 64
#define KSPLIT 7
#define N4 4096

typedef __attribute__((ext_vector_type(8))) short bf16x8;
typedef __attribute__((ext_vector_type(4))) float f32x4;

static __device__ __forceinline__ short f2bf(float x) {
    __hip_bfloat16 b = __float2bfloat16(x);   // RNE
    return *reinterpret_cast<short*>(&b);
}
static __device__ __forceinline__ unsigned pack2(float a, float b) {
    return (unsigned)(unsigned short)f2bf(a) | ((unsigned)(unsigned short)f2bf(b) << 16);
}

// ---- A1 (single-pass): per (tc,b): scores + context partial for 64 t's.
//      grid (4,128) x 256. enc read EXACTLY ONCE (score & ctx from registers).
__global__ void k_att1(const float* __restrict__ enc, const float* __restrict__ h,
                       float* __restrict__ scores_g, float* __restrict__ ctx_part) {
    const int tc = blockIdx.x;            // 0..3 (64-row chunk)
    const int b  = blockIdx.y;
    const int tid = threadIdx.x;
    const int wave = tid >> 6, lane = tid & 63;
    __shared__ float s_acc[4][1024];      // 16 KB

    const float4* h4 = (const float4*)(h + ((size_t)b << 10));
    float4 hv0 = h4[lane], hv1 = h4[lane + 64], hv2 = h4[lane + 128], hv3 = h4[lane + 192];

    float4 a0 = {0,0,0,0}, a1 = {0,0,0,0}, a2 = {0,0,0,0}, a3 = {0,0,0,0};
    const int t0 = (tc << 6) + (wave << 4);            // this wave's first row
    const float4* e4 = (const float4*)(enc + ((size_t)(b * Tc + t0) << 10));

    #pragma unroll 2
    for (int i = 0; i < 16; ++i) {
        float4 e0 = e4[lane], e1 = e4[lane + 64], e2 = e4[lane + 128], e3 = e4[lane + 192];
        e4 += 256;                                      // next row
        float d = e0.x*hv0.x + e0.y*hv0.y + e0.z*hv0.z + e0.w*hv0.w
                + e1.x*hv1.x + e1.y*hv1.y + e1.z*hv1.z + e1.w*hv1.w
                + e2.x*hv2.x + e2.y*hv2.y + e2.z*hv2.z + e2.w*hv2.w
                + e3.x*hv3.x + e3.y*hv3.y + e3.z*hv3.z + e3.w*hv3.w;
        #pragma unroll
        for (int off = 32; off; off >>= 1) d += __shfl_xor(d, off, 64);   // all lanes get d
        if (lane == 0) scores_g[(b << 8) + t0 + i] = d;
        a0.x += d*e0.x; a0.y += d*e0.y; a0.z += d*e0.z; a0.w += d*e0.w;
        a1.x += d*e1.x; a1.y += d*e1.y; a1.z += d*e1.z; a1.w += d*e1.w;
        a2.x += d*e2.x; a2.y += d*e2.y; a2.z += d*e2.z; a2.w += d*e2.w;
        a3.x += d*e3.x; a3.y += d*e3.y; a3.z += d*e3.z; a3.w += d*e3.w;
    }

    // cross-wave column sum: lane covers cols {4l, 256+4l, 512+4l, 768+4l}+0..3
    *(float4*)&s_acc[wave][lane << 2]         = a0;
    *(float4*)&s_acc[wave][256 + (lane << 2)] = a1;
    *(float4*)&s_acc[wave][512 + (lane << 2)] = a2;
    *(float4*)&s_acc[wave][768 + (lane << 2)] = a3;
    __syncthreads();
    float4 r0 = *(const float4*)&s_acc[0][tid << 2];
    float4 r1 = *(const float4*)&s_acc[1][tid << 2];
    float4 r2 = *(const float4*)&s_acc[2][tid << 2];
    float4 r3 = *(const float4*)&s_acc[3][tid << 2];
    float4 r;
    r.x = r0.x + r1.x + r2.x + r3.x;
    r.y = r0.y + r1.y + r2.y + r3.y;
    r.z = r0.z + r1.z + r2.z + r3.z;
    r.w = r0.w + r1.w + r2.w + r3.w;
    *(float4*)(ctx_part + (((size_t)(tc << 7) + b) << 10) + (tid << 2)) = r;
}

// ---- A2: reduce 4 ctx parts; softmax->attn; pack x_bf16 = [ctx, emb, h, 0] ----
__global__ void k_att2(const float* __restrict__ ctx_part, const float* __restrict__ scores_g,
                       const int* __restrict__ idx, const float* __restrict__ emb_table,
                       const float* __restrict__ h,
                       float* __restrict__ ctx_out, float* __restrict__ attn_out,
                       unsigned short* __restrict__ x_bf) {
    const int b = blockIdx.x;
    const int tid = threadIdx.x;
    __shared__ float red[256];

    float4 cv = {0.f, 0.f, 0.f, 0.f};
    #pragma unroll
    for (int tc = 0; tc < 4; ++tc) {
        float4 s = *(const float4*)(ctx_part + (((size_t)(tc << 7) + b) << 10) + (tid << 2));
        cv.x += s.x; cv.y += s.y; cv.z += s.z; cv.w += s.w;
    }
    *(float4*)(ctx_out + ((size_t)b << 10) + (tid << 2)) = cv;

    unsigned short* xb = x_bf + (size_t)b * KXP;
    uint2 p0; p0.x = pack2(cv.x, cv.y); p0.y = pack2(cv.z, cv.w);
    *(uint2*)&xb[tid << 2] = p0;

    int row = idx[b];
    for (int i = tid; i < Ec; i += 256)
        xb[Dc + i] = (unsigned short)f2bf(emb_table[(size_t)row * Ec + i]);

    float4 hv = *(const float4*)(h + ((size_t)b << 10) + (tid << 2));
    uint2 p1; p1.x = pack2(hv.x, hv.y); p1.y = pack2(hv.z, hv.w);
    *(uint2*)&xb[(Dc + Ec) + (tid << 2)] = p1;

    for (int i = tid; i < KXP - KREAL; i += 256) xb[KREAL + i] = 0;

    float v = scores_g[(b << 8) + tid];
    red[tid] = v;
    __syncthreads();
    for (int s = 128; s; s >>= 1) { if (tid < s) red[tid] = fmaxf(red[tid], red[tid + s]); __syncthreads(); }
    float m = red[0];
    __syncthreads();
    float e = __expf(v - m);
    red[tid] = e;
    __syncthreads();
    for (int s = 128; s; s >>= 1) { if (tid < s) red[tid] += red[tid + s]; __syncthreads(); }
    attn_out[(b << 8) + tid] = e / red[0];
}

// ---- Z: z partials, bf16 MFMA, LDS dbuf + early-issue. grid (64,7) x 512.
//      ONE barrier per K-step (dbuf write targets opposite buffer). ----
__global__ __launch_bounds__(512) void k_zgemm_mfma(
        const unsigned short* __restrict__ xbf, const float* __restrict__ Wl,
        const float* __restrict__ Ul, float* __restrict__ z_part) {
    __shared__ __align__(16) short blds[2 * 8 * 64 * 8];   // 16 KB
    const int tid  = threadIdx.x;
    const int wid  = tid >> 6;
    const int lane = tid & 63;
    const int g    = lane >> 4;
    const int r    = lane & 15;
    const int n0   = blockIdx.x << 6;     // 64-wide n tile
    const int ksp  = blockIdx.y;          // 0..6, steps ksp*6 .. ksp*6+5

    const int pr = tid >> 4;
    const int c  = tid & 15;
    const int kk = (pr << 1) & 31;
    const int gg = kk >> 3, jj = kk & 7;
    const int ks0 = pr >> 4;              // 0 or 1

    f32x4 acc[4] = {};
    const unsigned short* xrow = xbf + (size_t)((wid << 4) + r) * KXP;

    float4 wra[2], wrb[2];
    bf16x8 areg[2][2];

    auto loadWU = [&](int gk) -> float4 {
        if (gk < 1324) return *(const float4*)(Wl + (size_t)gk * N4 + n0 + (c << 2));
        if (gk < KREAL) return *(const float4*)(Ul + (size_t)(gk - 1324) * N4 + n0 + (c << 2));
        return float4{0.f, 0.f, 0.f, 0.f};
    };

    // prologue: tile 0
    {
        const int kt = (ksp * 6) << 6;
        wra[0] = loadWU(kt + (pr << 1));
        wrb[0] = loadWU(kt + (pr << 1) + 1);
        areg[0][0] = *(const bf16x8*)&xrow[kt + (g << 3)];
        areg[0][1] = *(const bf16x8*)&xrow[kt + 32 + (g << 3)];
    }

    #pragma unroll
    for (int t = 0; t < 6; ++t) {
        const int cur = t & 1;
        const int coff = cur << 12;       // shorts
        {
            const float av[4] = {wra[cur].x, wra[cur].y, wra[cur].z, wra[cur].w};
            const float bv[4] = {wrb[cur].x, wrb[cur].y, wrb[cur].z, wrb[cur].w};
            #pragma unroll
            for (int i = 0; i < 4; ++i) {
                int n = (c << 2) + i;
                int nt = n >> 4;
                int inner = (gg << 4) | (n & 15);
                int Xs = ((((ks0 << 2) + nt) << 6) | inner) ^ nt;
                *(unsigned*)&blds[coff + (Xs << 3) + jj] = pack2(av[i], bv[i]);
            }
        }
        if (t < 5) {
            const int kt = ((ksp * 6) + t + 1) << 6;
            wra[cur ^ 1] = loadWU(kt + (pr << 1));
            wrb[cur ^ 1] = loadWU(kt + (pr << 1) + 1);
            areg[cur ^ 1][0] = *(const bf16x8*)&xrow[kt + (g << 3)];
            areg[cur ^ 1][1] = *(const bf16x8*)&xrow[kt + 32 + (g << 3)];
        }
        __syncthreads();
        #pragma unroll
        for (int ks = 0; ks < 2; ++ks) {
            #pragma unroll
            for (int nt = 0; nt < 4; ++nt) {
                int Xs = ((((ks << 2) + nt) << 6) | lane) ^ nt;
                bf16x8 bfr = *(const bf16x8*)&blds[coff + (Xs << 3)];
                acc[nt] = __builtin_amdgcn_mfma_f32_16x16x32_bf16(areg[cur][ks], bfr, acc[nt], 0, 0, 0);
            }
        }
    }

    float* zp = z_part + ((size_t)ksp << 19);
    #pragma unroll
    for (int nt = 0; nt < 4; ++nt) {
        int col = n0 + (nt << 4) + r;
        #pragma unroll
        for (int j = 0; j < 4; ++j) {
            int rowm = (wid << 4) + (g << 2) + j;
            zp[((size_t)rowm << 12) + col] = acc[nt][j];
        }
    }
}

// ---- G: sum 7 partials + bias -> gates -> c_new, h_new, h_bf16 ----
__global__ void k_gates(const float* __restrict__ z_part, const float* __restrict__ b_lstm,
                        const float* __restrict__ c_in, float* __restrict__ h_new,
                        float* __restrict__ c_new, unsigned short* __restrict__ h_bf) {
    int i = blockIdx.x * 256 + threadIdx.x;    // < 131072
    int b = i >> 10, d = i & 1023;
    size_t base = ((size_t)b << 12) + d;
    float zi = b_lstm[d], zf = b_lstm[d + 1024], zg = b_lstm[d + 2048], zo = b_lstm[d + 3072];
    #pragma unroll
    for (int ks = 0; ks < KSPLIT; ++ks) {
        const float* zp = z_part + ((size_t)ks << 19);
        zi += zp[base];
        zf += zp[base + 1024];
        zg += zp[base + 2048];
        zo += zp[base + 3072];
    }
    float si = 1.f / (1.f + __expf(-zi));
    float sf = 1.f / (1.f + __expf(-zf));
    float so = 1.f / (1.f + __expf(-zo));
    float cn = sf * c_in[i] + si * tanhf(zg);
    float hn = so * tanhf(cn);
    c_new[i] = cn;
    h_new[i] = hn;
    h_bf[i] = (unsigned short)f2bf(hn);
}

// ---- L: logits, bf16 MFMA, K-step 128, LDS dbuf + early-issue. 500 x 512.
//      ONE barrier per K-step. ----
__global__ __launch_bounds__(512) void k_logits_mfma(
        const unsigned short* __restrict__ hbf, const float* __restrict__ Wd,
        const float* __restrict__ bd, float* __restrict__ out) {
    __shared__ __align__(16) short blds[2 * 16 * 64 * 8];   // 32 KB
    const int tid  = threadIdx.x;
    const int wid  = tid >> 6;
    const int lane = tid & 63;
    const int g    = lane >> 4;
    const int r    = lane & 15;
    const int n0   = blockIdx.x << 6;     // 64-wide n tile

    const int pr = tid >> 4;              // 0..31
    const int c  = tid & 15;
    const int kk = (pr << 1) & 31;
    const int gg = kk >> 3, jj = kk & 7;
    const int ksA = pr >> 4;              // task0: 0..1
    const int ksB = ksA + 2;              // task1: 2..3

    f32x4 acc[4] = {};
    const unsigned short* hrow = hbf + ((size_t)((wid << 4) + r) << 10);
    const float* wbase = Wd + (size_t)(pr << 1) * Vc + n0 + (c << 2);

    float4 wra[2], wrb[2], wrc[2], wrd[2];
    bf16x8 areg[2][4];

    // prologue: tile 0
    {
        wra[0] = *(const float4*)(wbase);
        wrb[0] = *(const float4*)(wbase + Vc);
        wrc[0] = *(const float4*)(wbase + (size_t)64 * Vc);
        wrd[0] = *(const float4*)(wbase + (size_t)65 * Vc);
        #pragma unroll
        for (int ks = 0; ks < 4; ++ks)
            areg[0][ks] = *(const bf16x8*)&hrow[(ks << 5) + (g << 3)];
    }

    #pragma unroll
    for (int t = 0; t < 8; ++t) {
        const int cur = t & 1;
        const int coff = cur << 13;       // shorts
        {
            const float a0[4] = {wra[cur].x, wra[cur].y, wra[cur].z, wra[cur].w};
            const float b0[4] = {wrb[cur].x, wrb[cur].y, wrb[cur].z, wrb[cur].w};
            const float c0[4] = {wrc[cur].x, wrc[cur].y, wrc[cur].z, wrc[cur].w};
            const float d0[4] = {wrd[cur].x, wrd[cur].y, wrd[cur].z, wrd[cur].w};
            #pragma unroll
            for (int i = 0; i < 4; ++i) {
                int n = (c << 2) + i;
                int nt = n >> 4;
                int inner = (gg << 4) | (n & 15);
                int XsA = ((((ksA << 2) + nt) << 6) | inner) ^ nt;
                int XsB = ((((ksB << 2) + nt) << 6) | inner) ^ nt;
                *(unsigned*)&blds[coff + (XsA << 3) + jj] = pack2(a0[i], b0[i]);
                *(unsigned*)&blds[coff + (XsB << 3) + jj] = pack2(c0[i], d0[i]);
            }
        }
        if (t < 7) {
            const float* wb2 = wbase + (size_t)((t + 1) << 7) * Vc;
            wra[cur ^ 1] = *(const float4*)(wb2);
            wrb[cur ^ 1] = *(const float4*)(wb2 + Vc);
            wrc[cur ^ 1] = *(const float4*)(wb2 + (size_t)64 * Vc);
            wrd[cur ^ 1] = *(const float4*)(wb2 + (size_t)65 * Vc);
            #pragma unroll
            for (int ks = 0; ks < 4; ++ks)
                areg[cur ^ 1][ks] = *(const bf16x8*)&hrow[((t + 1) << 7) + (ks << 5) + (g << 3)];
        }
        __syncthreads();
        #pragma unroll
        for (int ks = 0; ks < 4; ++ks) {
            #pragma unroll
            for (int nt = 0; nt < 4; ++nt) {
                int Xs = ((((ks << 2) + nt) << 6) | lane) ^ nt;
                bf16x8 bfr = *(const bf16x8*)&blds[coff + (Xs << 3)];
                acc[nt] = __builtin_amdgcn_mfma_f32_16x16x32_bf16(areg[cur][ks], bfr, acc[nt], 0, 0, 0);
            }
        }
    }

    #pragma unroll
    for (int nt = 0; nt < 4; ++nt) {
        int col = n0 + (nt << 4) + r;
        float bias = bd[col];
        #pragma unroll
        for (int j = 0; j < 4; ++j) {
            int row = (wid << 4) + (g << 2) + j;
            out[(size_t)row * Vc + col] = acc[nt][j] + bias;
        }
    }
}

extern "C" void kernel_launch(void* const* d_in, const int* in_sizes, int n_in,
                              void* d_out, int out_size, void* d_ws, size_t ws_size,
                              hipStream_t stream) {
    const int*   idx = (const int*)d_in[0];
    const float* enc = (const float*)d_in[1];
    const float* h   = (const float*)d_in[2];
    const float* c   = (const float*)d_in[3];
    const float* emb = (const float*)d_in[4];
    const float* Wl  = (const float*)d_in[5];
    const float* Ul  = (const float*)d_in[6];
    const float* bl  = (const float*)d_in[7];
    const float* Wd  = (const float*)d_in[8];
    const float* bd  = (const float*)d_in[9];

    float* out    = (float*)d_out;
    float* logits = out;                 // 4,096,000
    float* h_new  = out + 4096000;
    float* c_new  = out + 4227072;
    float* attn   = out + 4358144;
    float* ctx    = out + 4390912;

    // Scratch consumed BEFORE k_logits_mfma lives in the logits region;
    // anything k_logits_mfma READS lives in d_ws (it writes [0,4096000)).
    float*          ctx_part = out;                  // 4*131072 = 524,288
    float*          scores_g = out + 524288;         // 32,768 (ends 557,056)
    float*          z_part   = out;                  // 7*524,288 = 3,670,016
    unsigned short* x_bf16   = (unsigned short*)d_ws;            // 344,064 shorts
    unsigned short* h_bf16   = (unsigned short*)d_ws + 344064;   // 131,072 shorts (total 950,272 B)

    hipLaunchKernelGGL(k_att1, dim3(4, 128), dim3(256), 0, stream, enc, h, scores_g, ctx_part);
    hipLaunchKernelGGL(k_att2, dim3(128), dim3(256), 0, stream, ctx_part, scores_g, idx, emb, h,
                       ctx, attn, x_bf16);
    hipLaunchKernelGGL(k_zgemm_mfma, dim3(64, KSPLIT), dim3(512), 0, stream, x_bf16, Wl, Ul, z_part);
    hipLaunchKernelGGL(k_gates, dim3(512), dim3(256), 0, stream, z_part, bl, c, h_new, c_new, h_bf16);
    hipLaunchKernelGGL(k_logits_mfma, dim3(500), dim3(512), 0, stream, h_bf16, Wd, bd, logits);
}